// Round 4
// baseline (74.543 us; speedup 1.0000x reference)
//
#include <hip/hip_runtime.h>

#define STEP 10
#define NCH  256                 // 128*2 flattened channels = DP "batches"
#define BPB  4                   // batches per block (TLP: 8 waves -> 2/SIMD)
#define CSCL (-144.2695041f)     // -(1/GAMMA)*log2(e): scale into log2 domain
#define GLN2 (-0.00693147181f)   // -GAMMA*ln(2) == 1/CSCL (to 7e-10 rel)
#define BIGP (-1.442695041e12f)  // 1e10 * CSCL : boundary "BIG" in scaled domain
#define YOFF 256                 // pad: idx = YOFF + (s-2-2u) >= 0 for all u
#define YLDS 768
#define BNDSZ 424                // row-128 boundary value per diagonal s
#define LAGG 17                  // wave-1 lag in groups (17*8 = 136 >= 130 diags)

// exp2/log2 via raw ISA (no fast-math dependence)
__device__ __forceinline__ float fexp2(float x){ float r; asm("v_exp_f32 %0, %1" : "=v"(r) : "v"(x)); return r; }
__device__ __forceinline__ float flog2(float x){ float r; asm("v_log_f32 %0, %1" : "=v"(r) : "v"(x)); return r; }

// Whole-wave shift toward higher lanes (lane i <- lane i-1), VALU-speed DPP.
// Lane 0's result is garbage (bound_ctrl -> 0); caller overrides it via select.
__device__ __forceinline__ float dpp_shr1(float src){
    int s = __builtin_bit_cast(int, src);
    int r = __builtin_amdgcn_update_dpp(0, s, 0x138 /*wave_shr:1*/, 0xF, 0xF, true);
    return __builtin_bit_cast(float, r);
}

// Soft-DTW cell in the scaled domain R' = R*CSCL (CSCL < 0). No boundary mask:
// invalid cells self-perpetuate at ~BIGP (drift << 1e12) and contribute exactly
// 0.0f through exp2 in any valid cell — bit-identical to explicit masking.
__device__ __forceinline__ float dpcell(float up2, float up, float left,
                                        float xv, float yv) {
    float m  = fmaxf(fmaxf(up2, up), left);            // v_max3_f32
    float lo = fminf(fminf(up2, up), left);            // v_min3_f32
    float md = __builtin_amdgcn_fmed3f(up2, up, left); // v_med3_f32
    float e  = fexp2(lo - m) + fexp2(md - m) + 1.0f;
    float ls = flog2(e) + m;
    float d  = xv - yv;
    return fmaf(d * CSCL, d, ls);
}

// 4 batches per 512-thread block; per batch: two waves, 2 rows/thread.
// Wave 0 owns rows 1..128, wave 1 rows 129..256, lagging LAGG*8 diagonals and
// consuming the row-128 boundary from LDS (written >= 8 diagonals earlier).
// Boundary select happens at PRODUCTION time: bp(s+1) = (l==0)? bnd[s] : c1(s)
// shifted up one lane via DPP — so lane 0 of wave 1 at diag s+1 sees
// R'[128][s-128], the correct diag-s boundary cell (fixes R3's off-by-one).
__global__ __launch_bounds__(128 * BPB)
void softdtw_wave(const float* __restrict__ x, const float* __restrict__ y,
                  float* __restrict__ ws, int N) {
    const int u  = threadIdx.x & 127;    // thread within this batch's pair of waves
    const int g4 = threadIdx.x >> 7;     // sub-batch 0..3
    const int b  = blockIdx.x * BPB + g4;
    const int l  = u & 63;               // lane within wave
    const bool isw0 = (u < 64);

    __shared__ __align__(16) float YsP[BPB][YLDS];
    __shared__ float bnd[BPB][BNDSZ];
    float* Ys   = YsP[g4];
    float* bndp = bnd[g4];
    for (int j = u; j < YLDS;  j += 128) Ys[j]   = 0.0f;
    for (int j = u; j < BNDSZ; j += 128) bndp[j] = BIGP;
    __syncthreads();
    for (int j = u; j < N; j += 128) Ys[YOFF + j] = y[j * STEP * NCH + b];
    __syncthreads();

    const int i0 = 2 * u + 1;            // rows i0, i0+1
    float xv0 = (i0     <= N) ? x[(i0 - 1) * STEP * NCH + b] : 0.f;
    float xv1 = (i0 + 1 <= N) ? x[(i0    ) * STEP * NCH + b] : 0.f;

    // scaled DP state entering diag s:
    //   sp0=R'(i0,s-1-i0)  sp1=R'(i0+1,s-2-i0)  sq0=R'(i0,s-2-i0)
    //   bp =R'(i0-1,s-i0)  bq =R'(i0-1,s-1-i0)
    float sp0 = BIGP, sp1 = BIGP, sq0 = BIGP;
    float bp  = BIGP;
    float bq  = (u == 0) ? 0.0f : BIGP;  // R'[0][0] seed enters at s=2
    float w0v = 0.f, w1v = 0.f;          // y window: Y[j0-1], Y[j0-2]

    const int smax = 2 * N;
    const int NG0  = (127 + N + 7) >> 3;        // wave-0 groups (diags 2..128+N)
    const int NG1  = (smax - 129 + 7) >> 3;     // wave-1 groups (diags 130..2N)
    const int NGRP = (NG0 > LAGG + NG1) ? NG0 : (LAGG + NG1);

    #define STEPJ(WNEW, HJ, J) do {                                   \
        w1v = w0v; w0v = (WNEW);                                      \
        float c1 = dpcell(sq0, sp0, sp1, xv1, w1v);                   \
        float c0 = dpcell(bq,  bp,  sp0, xv0, w0v);                   \
        float sh = dpp_shr1(c1);                                      \
        if (isw0 && l == 63) bndp[sb + (J)] = c1;                     \
        sq0 = sp0; sp0 = c0; sp1 = c1;                                \
        bq = bp;                                                      \
        bp = (l == 0) ? (HJ) : sh;                                    \
        if (sb + (J) == smax) {                                       \
            if      (i0     == N) ws[b] = c0 * GLN2;                  \
            else if (i0 + 1 == N) ws[b] = c1 * GLN2;                  \
        }                                                             \
    } while (0)

    for (int k = 0; k < NGRP; ++k) {
        __syncthreads();                 // fences wave-0's older bnd writes
        const int  m   = isw0 ? k : (k - LAGG);
        const bool act = isw0 ? (k < NG0) : (m >= 0 && m < NG1);
        if (act) {
            const int sb = (isw0 ? 2 : 130) + (m << 3);   // first diag of group
            // y for steps 0..7: Y[sb-2-2u + J] (8B-aligned float2 reads)
            const float2* yp = (const float2*)(Ys + YOFF + (sb - 2)) - u;
            float2 ya = yp[0], yb2 = yp[1], yc = yp[2], yd = yp[3];
            // boundary values consumed at PRODUCTION time (see header comment):
            // step J's select uses bnd[sb+J], the diag-(sb+J) row-128 cell,
            // which becomes bp for diag sb+J+1.  Reads [sb, sb+7]; wave-0
            // concurrently writes [sb+136+8, ...] — disjoint, barrier-fenced.
            float h0,h1,h2,h3,h4,h5,h6,h7;
            if (isw0) { h0=h1=h2=h3=h4=h5=h6=h7 = BIGP; }
            else {
                h0=bndp[sb+0]; h1=bndp[sb+1]; h2=bndp[sb+2]; h3=bndp[sb+3];
                h4=bndp[sb+4]; h5=bndp[sb+5]; h6=bndp[sb+6]; h7=bndp[sb+7];
                if (m == 0 && l == 0) bp = bndp[sb - 1];  // seed R'(128,1)@diag129
            }
            STEPJ(ya.x,  h0, 0); STEPJ(ya.y,  h1, 1);
            STEPJ(yb2.x, h2, 2); STEPJ(yb2.y, h3, 3);
            STEPJ(yc.x,  h4, 4); STEPJ(yc.y,  h5, 5);
            STEPJ(yd.x,  h6, 6); STEPJ(yd.y,  h7, 7);
        }
    }
    #undef STEPJ
}

// Deterministic 256 -> 1 reduction (shuffle within wave64, LDS across 4 waves)
__global__ __launch_bounds__(256)
void reduce256(const float* __restrict__ ws, float* __restrict__ out) {
    const int tid = threadIdx.x;
    float v = ws[tid];
    #pragma unroll
    for (int off = 32; off > 0; off >>= 1)
        v += __shfl_down(v, off, 64);
    __shared__ float partial[4];
    if ((tid & 63) == 0) partial[tid >> 6] = v;
    __syncthreads();
    if (tid == 0) out[0] = (partial[0] + partial[1]) + (partial[2] + partial[3]);
}

extern "C" void kernel_launch(void* const* d_in, const int* in_sizes, int n_in,
                              void* d_out, int out_size, void* d_ws, size_t ws_size,
                              hipStream_t stream) {
    const float* x = (const float*)d_in[0];
    const float* y = (const float*)d_in[1];
    float* out = (float*)d_out;
    float* ws  = (float*)d_ws;

    const int T = in_sizes[0] / NCH;            // 2048 frames
    const int L = (T + STEP - 1) / STEP;        // 205 subsampled frames

    softdtw_wave<<<dim3(NCH / BPB), dim3(128 * BPB), 0, stream>>>(x, y, ws, L);
    reduce256<<<dim3(1), dim3(256), 0, stream>>>(ws, out);
}

// Round 5
// 43.026 us; speedup vs baseline: 1.7325x; 1.7325x over previous
//
#include <hip/hip_runtime.h>

#define STEP 10
#define NCH  256                 // 128*2 flattened channels = DP "batches"
#define CSCL (-144.2695041f)     // -(1/GAMMA)*log2(e): scale into log2 domain
#define GLN2 (-0.00693147181f)   // -GAMMA*ln(2) == 1/CSCL (to 7e-10 rel)
#define BIGP (-1.442695041e12f)  // 1e10 * CSCL : boundary "BIG" in scaled domain
#define YOFF 64                  // pad: y idx = sb-2-64w-l + J >= -63
#define YLDS 384                 // YOFF + N + 80 for N <= 240
#define BNDSZ 472                // absolute-diag-indexed boundary ring (no reuse)
#define NW   4                   // waves per batch

// exp2/log2 via raw ISA (no fast-math dependence)
__device__ __forceinline__ float fexp2(float x){ float r; asm("v_exp_f32 %0, %1" : "=v"(r) : "v"(x)); return r; }
__device__ __forceinline__ float flog2(float x){ float r; asm("v_log_f32 %0, %1" : "=v"(r) : "v"(x)); return r; }

// Whole-wave shift toward higher lanes (lane i <- lane i-1), VALU-speed DPP.
// Lane 0 gets 0 (bound_ctrl); caller overrides via select. Validated in R4.
__device__ __forceinline__ float dpp_shr1(float src){
    int s = __builtin_bit_cast(int, src);
    int r = __builtin_amdgcn_update_dpp(0, s, 0x138 /*wave_shr:1*/, 0xF, 0xF, true);
    return __builtin_bit_cast(float, r);
}

// Soft-DTW cell in the scaled domain R' = R*CSCL (CSCL < 0). No boundary mask:
// invalid cells self-perpetuate at ~BIGP (|drift| << ULP(1e12)) and contribute
// exactly 0.0f through exp2 in any valid cell — identical to explicit masking.
__device__ __forceinline__ float dpcell(float up2, float up, float left,
                                        float xv, float yv) {
    float m  = fmaxf(fmaxf(up2, up), left);            // v_max3_f32
    float lo = fminf(fminf(up2, up), left);            // v_min3_f32
    float md = __builtin_amdgcn_fmed3f(up2, up, left); // v_med3_f32
    float e  = fexp2(lo - m) + fexp2(md - m) + 1.0f;
    float ls = flog2(e) + m;
    float d  = xv - yv;
    return fmaf(d * CSCL, d, ls);
}

// 4 waves per batch (256 threads, 1 block/CU), ONE row per lane: wave w owns
// rows 64w+1..64w+64. No barriers in the main loop: wave w consumes the
// row-64w boundary stream written by wave w-1 into bnd[w-1][diag], paced by a
// monotone LDS progress counter (acquire/release, workgroup scope). bnd slots
// are absolute-diag indexed (never reused) so producers NEVER wait on
// consumers — the R4 convoy is structurally gone. Steady-state lag between
// adjacent waves = 8 groups (64 diagonals).
__global__ __launch_bounds__(256)
void softdtw_wave(const float* __restrict__ x, const float* __restrict__ y,
                  float* __restrict__ ws, int N) {
    const int b = blockIdx.x;
    const int t = threadIdx.x;          // 0..255
    const int l = t & 63;               // lane within wave
    const int w = t >> 6;               // wave 0..3

    __shared__ __align__(16) float Ys[YLDS];
    __shared__ float bnd[NW - 1][BNDSZ];
    __shared__ int prog[NW - 1];

    for (int j = t; j < YLDS; j += 256) Ys[j] = 0.f;
    float* bf = &bnd[0][0];
    for (int j = t; j < (NW - 1) * BNDSZ; j += 256) bf[j] = BIGP;
    if (t < NW - 1) prog[t] = 0;
    __syncthreads();
    for (int j = t; j < N; j += 256) Ys[YOFF + j] = y[j * STEP * NCH + b];
    __syncthreads();                    // the only block-wide barriers (startup)

    const int i = 64 * w + l + 1;       // my row
    const float xv = (i <= N) ? x[(i - 1) * STEP * NCH + b] : 0.f;

    // scaled DP state entering diag s:
    //   sp = R'(i, s-1-i)   bp = R'(i-1, s-1-(i-1))   bq = R'(i-1, s-2-(i-1))
    float sp = BIGP, bp = BIGP;
    float bq = (t == 0) ? 0.0f : BIGP;  // R'[0][0] seed enters at s=2

    const int smax = 2 * N;
    const int NG   = (N + 63 + 7) >> 3; // groups of 8 diagonals per wave
    const int sb0  = 64 * w + 2;        // first diagonal of this wave
    const bool prod = (w < NW - 1);
    const bool cons = (w > 0);
    const int progFinal = 64 * (w - 1) + 2 + NG * 8 - 1;  // producer's last publish

    // per-lane y pointer: step J of group at sb reads Y[sb+J - i - 1]
    const float* yb = Ys + (YOFF - l);  // == YOFF + sb0-2-64w - l

    #define STEPJ(YV, HJ, CJ, J) do {                              \
        CJ = dpcell(bq, bp, sp, xv, (YV));                         \
        float sh = dpp_shr1(CJ);                                   \
        bq = bp;                                                   \
        bp = (l == 0) ? (HJ) : sh;                                 \
        sp = CJ;                                                   \
        if (sb + (J) == smax) { if (i == N) ws[b] = CJ * GLN2; }   \
    } while (0)

    for (int m = 0; m < NG; ++m) {
        const int sb = sb0 + 8 * m;
        // issue y reads before the poll so their latency hides under the spin
        float y0 = yb[0], y1 = yb[1], y2 = yb[2], y3 = yb[3];
        float y4 = yb[4], y5 = yb[5], y6 = yb[6], y7 = yb[7];
        yb += 8;

        float h0, h1, h2, h3, h4, h5, h6, h7;
        if (cons) {
            const int need = min(sb + 7, progFinal);   // cap: beyond-span = wall
            while (__hip_atomic_load(&prog[w - 1], __ATOMIC_ACQUIRE,
                                     __HIP_MEMORY_SCOPE_WORKGROUP) < need)
                __builtin_amdgcn_s_sleep(1);
            const float* bb = bnd[w - 1];
            if (m == 0 && l == 0) bp = bb[sb - 1];     // seed R'(64w, 1) @ first diag
            h0 = bb[sb + 0]; h1 = bb[sb + 1]; h2 = bb[sb + 2]; h3 = bb[sb + 3];
            h4 = bb[sb + 4]; h5 = bb[sb + 5]; h6 = bb[sb + 6]; h7 = bb[sb + 7];
        } else {
            h0 = h1 = h2 = h3 = h4 = h5 = h6 = h7 = BIGP;  // row-0 wall
        }

        float c0, c1, c2, c3, c4, c5, c6, c7;
        STEPJ(y0, h0, c0, 0); STEPJ(y1, h1, c1, 1);
        STEPJ(y2, h2, c2, 2); STEPJ(y3, h3, c3, 3);
        STEPJ(y4, h4, c4, 4); STEPJ(y5, h5, c5, 5);
        STEPJ(y6, h6, c6, 6); STEPJ(y7, h7, c7, 7);

        // batched boundary publish: one exec-mask toggle, 8 writes, release
        if (prod && l == 63) {
            float* bw = &bnd[w][sb];
            bw[0] = c0; bw[1] = c1; bw[2] = c2; bw[3] = c3;
            bw[4] = c4; bw[5] = c5; bw[6] = c6; bw[7] = c7;
            __hip_atomic_store(&prog[w], sb + 7, __ATOMIC_RELEASE,
                               __HIP_MEMORY_SCOPE_WORKGROUP);
        }
    }
    #undef STEPJ
}

// Deterministic 256 -> 1 reduction (shuffle within wave64, LDS across 4 waves)
__global__ __launch_bounds__(256)
void reduce256(const float* __restrict__ ws, float* __restrict__ out) {
    const int tid = threadIdx.x;
    float v = ws[tid];
    #pragma unroll
    for (int off = 32; off > 0; off >>= 1)
        v += __shfl_down(v, off, 64);
    __shared__ float partial[4];
    if ((tid & 63) == 0) partial[tid >> 6] = v;
    __syncthreads();
    if (tid == 0) out[0] = (partial[0] + partial[1]) + (partial[2] + partial[3]);
}

extern "C" void kernel_launch(void* const* d_in, const int* in_sizes, int n_in,
                              void* d_out, int out_size, void* d_ws, size_t ws_size,
                              hipStream_t stream) {
    const float* x = (const float*)d_in[0];
    const float* y = (const float*)d_in[1];
    float* out = (float*)d_out;
    float* ws  = (float*)d_ws;

    const int T = in_sizes[0] / NCH;            // 2048 frames
    const int L = (T + STEP - 1) / STEP;        // 205 subsampled frames

    softdtw_wave<<<dim3(NCH), dim3(256), 0, stream>>>(x, y, ws, L);
    reduce256<<<dim3(1), dim3(256), 0, stream>>>(ws, out);
}